// Round 1
// baseline (812.296 us; speedup 1.0000x reference)
//
#include <hip/hip_runtime.h>

#define BSZ 32
#define DIMD 256
#define WW 2048
#define SLOTS 1024
#define NROWS (BSZ*WW)
#define LOG_SLOTS 6.931471805599453f

#define ZQ_N (BSZ*DIMD*WW)
#define IDX_OFF ZQ_N
#define KL_OFF (ZQ_N + NROWS)
#define CM_OFF (KL_OFF + 1)

// workspace byte offsets
#define WS_CH   0u
#define WS_CL   524288u
#define WS_PV   1048576u
#define WS_CBSQ 1572864u
#define WS_TOP  1576960u
#define WS_YSC  2625536u
#define WS_NEED (2625536ull + 268435456ull)

typedef _Float16 half2_t __attribute__((ext_vector_type(2)));
typedef _Float16 half8_t __attribute__((ext_vector_type(8)));
typedef float v4f __attribute__((ext_vector_type(4)));

__device__ __forceinline__ void pmerge(float& m, float& s, float& t, float om, float os, float ot) {
  float M = fmaxf(m, om);
  float ea = __expf(m - M), eb = __expf(om - M);
  s = s * ea + os * eb;
  t = t * ea + ot * eb;
  m = M;
}

// merge two sorted top-3 lists (indices kept for top-2); ties -> smaller index wins
__device__ __forceinline__ void top3_merge(float& v1, float& i1, float& v2, float& i2, float& v3,
                                           float ov1, float oi1, float ov2, float oi2, float ov3) {
  bool sw = (ov1 > v1) || (ov1 == v1 && oi1 < i1);
  float a1v = sw ? ov1 : v1, a1i = sw ? oi1 : i1;
  float a2v = sw ? ov2 : v2, a2i = sw ? oi2 : i2;
  float a3v = sw ? ov3 : v3;
  float b1v = sw ? v1 : ov1, b1i = sw ? i1 : oi1;
  float b2v = sw ? v2 : ov2;
  bool a2w = (a2v > b1v) || (a2v == b1v && a2i < b1i);
  v1 = a1v; i1 = a1i;
  v2 = a2w ? a2v : b1v;
  i2 = a2w ? a2i : b1i;
  v3 = a2w ? fmaxf(a3v, b1v) : fmaxf(a2v, b2v);
}

__global__ void k0_zero(float* out) { out[KL_OFF] = 0.f; out[CM_OFF] = 0.f; }

// pack codebook into MFMA B-fragment streams (fp16 hi/lo for distances; fp16 for PV) + fp64 cbsq
__global__ void k2_pack(const float* __restrict__ cb, _Float16* __restrict__ chs,
                        _Float16* __restrict__ cls, _Float16* __restrict__ pvs,
                        float* __restrict__ cbsq) {
  const int tid = blockIdx.x * 256 + threadIdx.x;
  if (tid < 32768) {
    const int lane = tid & 63;
    {
      const int ks = (tid >> 6) & 7, sblk = tid >> 9;
      const int col = sblk * 16 + (lane & 15);
      const int k0 = ks * 32 + (lane >> 4) * 8;
      half8_t vh, vl;
#pragma unroll
      for (int j = 0; j < 8; ++j) {
        const float v = cb[(size_t)col * DIMD + k0 + j];
        const _Float16 h = (_Float16)v;
        vh[j] = h;
        vl[j] = (_Float16)(v - (float)h);
      }
      *(half8_t*)&chs[(size_t)tid * 8] = vh;
      *(half8_t*)&cls[(size_t)tid * 8] = vl;
    }
    {
      const int ks2 = (tid >> 6) & 31, dblk = tid >> 11;
      const int d = dblk * 16 + (lane & 15);
      const int s0 = ks2 * 32 + (lane >> 4) * 8;
      half8_t vp;
#pragma unroll
      for (int j = 0; j < 8; ++j)
        vp[j] = (_Float16)cb[(size_t)(s0 + j) * DIMD + d];
      *(half8_t*)&pvs[(size_t)tid * 8] = vp;
    }
  }
  if (tid < SLOTS) {
    double a = 0.0;
    for (int i = 0; i < DIMD; ++i) { const double v = (double)cb[(size_t)tid * DIMD + i]; a += v * v; }
    cbsq[tid] = (float)a;
  }
}

// main: distances (fp16-split MFMA) + online probs-path stats + top3/argmax + ysc materialization
__launch_bounds__(256, 2)
__global__ void k3_main(const float* __restrict__ z_e, const float* __restrict__ gum,
                        const _Float16* __restrict__ chs, const _Float16* __restrict__ cls,
                        const float* __restrict__ cbsq, float* __restrict__ ysc,
                        float* __restrict__ topw, float* __restrict__ out) {
  __shared__ _Float16 zh[64 * 256];
  __shared__ _Float16 zl[64 * 256];
  __shared__ float zsq[64];
  __shared__ float red4[4][64];
  __shared__ float mbuf[64][2][8];
  __shared__ float klcm[2];

  const int t = threadIdx.x;
  const int blk = blockIdx.x;
  const int r0 = blk * 64;
  const int b = r0 >> 11;
  const int w0 = r0 & 2047;

  // ---- stage z tile (transpose + fp16 split, XOR-swizzled chunks) ----
  {
    const int w = t & 63, dq = t >> 6;
    const float* src = z_e + (size_t)b * DIMD * WW + w0 + w;
    float acc = 0.f;
#pragma unroll 4
    for (int j = 0; j < 32; ++j) {
      const int d0 = dq * 64 + j * 2;
      const float a0 = src[(size_t)d0 * WW];
      const float a1 = src[(size_t)(d0 + 1) * WW];
      acc += a0 * a0 + a1 * a1;
      const _Float16 h0 = (_Float16)a0, h1 = (_Float16)a1;
      const _Float16 e0 = (_Float16)(a0 - (float)h0), e1 = (_Float16)(a1 - (float)h1);
      const int idx = w * 256 + (((d0 >> 3) ^ (w & 7)) * 8) + (d0 & 7);
      *(half2_t*)&zh[idx] = half2_t{h0, h1};
      *(half2_t*)&zl[idx] = half2_t{e0, e1};
    }
    red4[dq][w] = acc;
  }
  if (t == 0) { klcm[0] = 0.f; klcm[1] = 0.f; }
  __syncthreads();
  if (t < 64) zsq[t] = (red4[0][t] + red4[1][t]) + (red4[2][t] + red4[3][t]);
  __syncthreads();

  const int wv = t >> 6, lane = t & 63;
  const int rh = wv >> 1, sh = wv & 1;
  const int l15 = lane & 15, lq = lane >> 4;

  float zs[2][4];
#pragma unroll
  for (int r = 0; r < 2; ++r)
#pragma unroll
    for (int g = 0; g < 4; ++g)
      zs[r][g] = zsq[rh * 32 + r * 16 + lq * 4 + g];

  float m1[8], s1[8], t1[8], v1[8], v2[8], v3[8], i1[8], i2[8];
#pragma unroll
  for (int j = 0; j < 8; ++j) {
    m1[j] = -1e30f; s1[j] = 0.f; t1[j] = 0.f;
    v1[j] = -1e30f; v2[j] = -1e30f; v3[j] = -1e30f; i1[j] = 0.f; i2[j] = 0.f;
  }

  const float* gbase = gum + (size_t)r0 * SLOTS;
  float* ybase = ysc + (size_t)r0 * SLOTS;

#pragma unroll 1
  for (int cf2 = 0; cf2 < 16; ++cf2) {
    const int sblk0 = sh * 32 + cf2 * 2;
    v4f acc[2][2];
#pragma unroll
    for (int c = 0; c < 2; ++c)
#pragma unroll
      for (int r = 0; r < 2; ++r) acc[c][r] = v4f{0.f, 0.f, 0.f, 0.f};

#pragma unroll
    for (int ks = 0; ks < 8; ++ks) {
      half8_t ah[2], al[2];
#pragma unroll
      for (int r = 0; r < 2; ++r) {
        const int row = (rh * 2 + r) * 16 + l15;
        const int k0 = ks * 32 + lq * 8;
        const int idx = row * 256 + (((k0 >> 3) ^ (row & 7)) * 8);
        ah[r] = *(const half8_t*)&zh[idx];
        al[r] = *(const half8_t*)&zl[idx];
      }
#pragma unroll
      for (int c = 0; c < 2; ++c) {
        const size_t boff = ((size_t)(sblk0 + c) * 8 + ks) * 512 + (size_t)lane * 8;
        const half8_t bh = *(const half8_t*)&chs[boff];
        const half8_t bl = *(const half8_t*)&cls[boff];
#pragma unroll
        for (int r = 0; r < 2; ++r) {
          acc[c][r] = __builtin_amdgcn_mfma_f32_16x16x32_f16(ah[r], bh, acc[c][r], 0, 0, 0);
          acc[c][r] = __builtin_amdgcn_mfma_f32_16x16x32_f16(al[r], bh, acc[c][r], 0, 0, 0);
          acc[c][r] = __builtin_amdgcn_mfma_f32_16x16x32_f16(ah[r], bl, acc[c][r], 0, 0, 0);
        }
      }
    }
    // epilogue: d, ysc, online stats, top3
#pragma unroll
    for (int c = 0; c < 2; ++c) {
      const int col = (sblk0 + c) * 16 + l15;
      const float cq = cbsq[col];
      const float fc = (float)col;
#pragma unroll
      for (int r = 0; r < 2; ++r) {
#pragma unroll
        for (int g = 0; g < 4; ++g) {
          const int row = rh * 32 + r * 16 + lq * 4 + g;
          const float dd = cq + zs[r][g] - 2.f * acc[c][r][g];
          const float gv = gbase[(size_t)row * SLOTS + col];
          const float y = 2.f * (gv - dd);
          ybase[(size_t)row * SLOTS + col] = y;
          const int j = r * 4 + g;
          const float lv = -dd;
          const float M = fmaxf(m1[j], lv);
          const float ea = __expf(m1[j] - M);
          const float eb = __expf(lv - M);
          s1[j] = s1[j] * ea + eb;
          t1[j] = t1[j] * ea + eb * dd;
          m1[j] = M;
          const bool g1 = (y > v1[j]);
          const bool g2 = (y > v2[j]);
          const bool g3 = (y > v3[j]);
          v3[j] = g2 ? v2[j] : (g3 ? y : v3[j]);
          v2[j] = g1 ? v1[j] : (g2 ? y : v2[j]);
          i2[j] = g1 ? i1[j] : (g2 ? fc : i2[j]);
          v1[j] = g1 ? y : v1[j];
          i1[j] = g1 ? fc : i1[j];
        }
      }
    }
  }

  // cross-lane merge within each 16-lane group (lanes share the same 8 rows)
#pragma unroll
  for (int mk = 1; mk < 16; mk <<= 1) {
#pragma unroll
    for (int j = 0; j < 8; ++j) {
      const float om = __shfl_xor(m1[j], mk);
      const float os = __shfl_xor(s1[j], mk);
      const float ot = __shfl_xor(t1[j], mk);
      pmerge(m1[j], s1[j], t1[j], om, os, ot);
      const float ov1 = __shfl_xor(v1[j], mk);
      const float oi1 = __shfl_xor(i1[j], mk);
      const float ov2 = __shfl_xor(v2[j], mk);
      const float oi2 = __shfl_xor(i2[j], mk);
      const float ov3 = __shfl_xor(v3[j], mk);
      top3_merge(v1[j], i1[j], v2[j], i2[j], v3[j], ov1, oi1, ov2, oi2, ov3);
    }
  }
  if (l15 == 0) {
#pragma unroll
    for (int j = 0; j < 8; ++j) {
      const int row = rh * 32 + (j >> 2) * 16 + lq * 4 + (j & 3);
      mbuf[row][sh][0] = m1[j]; mbuf[row][sh][1] = s1[j]; mbuf[row][sh][2] = t1[j];
      mbuf[row][sh][3] = v1[j]; mbuf[row][sh][4] = v2[j]; mbuf[row][sh][5] = v3[j];
      mbuf[row][sh][6] = i1[j]; mbuf[row][sh][7] = i2[j];
    }
  }
  __syncthreads();
  if (t < 64) {
    float m = mbuf[t][0][0], s = mbuf[t][0][1], tt = mbuf[t][0][2];
    pmerge(m, s, tt, mbuf[t][1][0], mbuf[t][1][1], mbuf[t][1][2]);
    const float commit_row = tt / s;
    const float lse = m + logf(s);
    const float kl_row = -commit_row - lse + LOG_SLOTS;
    float V1 = mbuf[t][0][3], V2 = mbuf[t][0][4], V3 = mbuf[t][0][5];
    float I1 = mbuf[t][0][6], I2 = mbuf[t][0][7];
    top3_merge(V1, I1, V2, I2, V3,
               mbuf[t][1][3], mbuf[t][1][6], mbuf[t][1][4], mbuf[t][1][7], mbuf[t][1][5]);
    out[IDX_OFF + r0 + t] = I1;
    float4 tv; tv.x = V1; tv.y = V2; tv.z = V3; tv.w = I2;
    *(float4*)&topw[(size_t)(r0 + t) * 4] = tv;
    atomicAdd(&klcm[0], kl_row);
    atomicAdd(&klcm[1], commit_row);
  }
  __syncthreads();
  if (t == 0) {
    atomicAdd(&out[KL_OFF], klcm[0] * 0.03125f);
    atomicAdd(&out[CM_OFF], klcm[1] * 0.03125f);
  }
}

// soft path: u = exp(ysc - y1), P@V via MFMA (computes z_q^T directly -> coalesced stores)
__launch_bounds__(256, 2)
__global__ void k4_pv(const float* __restrict__ ysc, const float* __restrict__ topw,
                      const _Float16* __restrict__ pvs, float* __restrict__ out) {
  __shared__ _Float16 u[64 * 128];
  __shared__ float y1s[64];
  __shared__ float s2s[64];
  const int t = threadIdx.x;
  const int blk = blockIdx.x;
  const int r0 = blk * 64;
  const int b = r0 >> 11;
  const int w0 = r0 & 2047;
  if (t < 64) { y1s[t] = topw[(size_t)(r0 + t) * 4]; s2s[t] = 0.f; }
  __syncthreads();
  const int wv = t >> 6, lane = t & 63, l15 = lane & 15, lq = lane >> 4;
  v4f acc[4][4];
#pragma unroll
  for (int a = 0; a < 4; ++a)
#pragma unroll
    for (int c = 0; c < 4; ++c) acc[a][c] = v4f{0.f, 0.f, 0.f, 0.f};
  const float* ybase = ysc + (size_t)r0 * SLOTS;
#pragma unroll 1
  for (int ch = 0; ch < 8; ++ch) {
#pragma unroll 1
    for (int p = 0; p < 16; ++p) {
      const int row = p * 4 + wv;
      const int s = lane * 2;
      const float2 yv = *(const float2*)&ybase[(size_t)row * SLOTS + ch * 128 + s];
      const float y1 = y1s[row];
      const float u0 = __expf(yv.x - y1);
      const float u1 = __expf(yv.y - y1);
      float ss = u0 + u1;
#pragma unroll
      for (int mk = 1; mk < 64; mk <<= 1) ss += __shfl_xor(ss, mk);
      if (lane == 0) atomicAdd(&s2s[row], ss);
      const int idx = row * 128 + (((s >> 3) ^ (row & 7)) * 8) + (s & 7);
      *(half2_t*)&u[idx] = half2_t{(_Float16)u0, (_Float16)u1};
    }
    __syncthreads();
#pragma unroll
    for (int ks = 0; ks < 4; ++ks) {
      half8_t bu[4];
#pragma unroll
      for (int wf = 0; wf < 4; ++wf) {
        const int row = wf * 16 + l15;
        const int k0 = ks * 32 + lq * 8;
        bu[wf] = *(const half8_t*)&u[row * 128 + (((k0 >> 3) ^ (row & 7)) * 8)];
      }
#pragma unroll
      for (int df = 0; df < 4; ++df) {
        const size_t aoff = ((size_t)((wv * 4 + df) * 32 + (ch * 4 + ks)) * 64 + lane) * 8;
        const half8_t av = *(const half8_t*)&pvs[aoff];
#pragma unroll
        for (int wf = 0; wf < 4; ++wf)
          acc[df][wf] = __builtin_amdgcn_mfma_f32_16x16x32_f16(av, bu[wf], acc[df][wf], 0, 0, 0);
      }
    }
    __syncthreads();
  }
#pragma unroll
  for (int df = 0; df < 4; ++df)
#pragma unroll
    for (int wf = 0; wf < 4; ++wf)
#pragma unroll
      for (int g = 0; g < 4; ++g) {
        const int d = wv * 64 + df * 16 + lq * 4 + g;
        const int w = wf * 16 + l15;
        out[((size_t)b * DIMD + d) * WW + w0 + w] = acc[df][wf][g] / s2s[w];
      }
}

// fp64 argmax repair for near-tie rows
__global__ void k5_repair(const float* __restrict__ z_e, const float* __restrict__ cb,
                          const float* __restrict__ gum, const float* __restrict__ topw,
                          float* __restrict__ out) {
  const int wv = threadIdx.x >> 6, lane = threadIdx.x & 63;
#pragma unroll 1
  for (int rr = 0; rr < 64; ++rr) {
    const int r = blockIdx.x * 256 + wv * 64 + rr;
    const float4 tw = *(const float4*)&topw[(size_t)r * 4];
    if (tw.x - tw.y >= 0.02f) continue;
    const int b = r >> 11, w = r & 2047;
    double zd[4]; double zq = 0.0;
#pragma unroll
    for (int i = 0; i < 4; ++i) {
      const float zz = z_e[((size_t)b * DIMD + lane + i * 64) * WW + w];
      zd[i] = (double)zz; zq += zd[i] * zd[i];
    }
#pragma unroll
    for (int mk = 1; mk < 64; mk <<= 1) zq += __shfl_xor(zq, mk);
    const int c1 = (int)out[IDX_OFF + r];
    const int c2 = (int)tw.w;
    const bool full = (tw.x - tw.z < 0.02f);
    double bestv = -1e300; int besti = 0;
    const int nc = full ? SLOTS : 2;
    for (int ci = 0; ci < nc; ++ci) {
      const int s = full ? ci : (ci == 0 ? c1 : c2);
      double dot = 0.0, csq = 0.0;
#pragma unroll
      for (int i = 0; i < 4; ++i) {
        const double cv = (double)cb[(size_t)s * DIMD + lane + i * 64];
        dot += zd[i] * cv; csq += cv * cv;
      }
#pragma unroll
      for (int mk = 1; mk < 64; mk <<= 1) { dot += __shfl_xor(dot, mk); csq += __shfl_xor(csq, mk); }
      const double y = 2.0 * ((double)gum[(size_t)r * SLOTS + s] - (csq + zq - 2.0 * dot));
      if (y > bestv || (y == bestv && s < besti)) { bestv = y; besti = s; }
    }
    if (lane == 0) out[IDX_OFF + r] = (float)besti;
  }
}

extern "C" void kernel_launch(void* const* d_in, const int* in_sizes, int n_in,
                              void* d_out, int out_size, void* d_ws, size_t ws_size,
                              hipStream_t stream) {
  const float* z_e = (const float*)d_in[0];
  const float* cb  = (const float*)d_in[1];
  const float* gum = (const float*)d_in[2];
  float* out = (float*)d_out;
  char* ws = (char*)d_ws;
  if (ws_size < WS_NEED) {
    // insufficient scratch for ysc materialization: emit zeros (clean failure signature)
    hipMemsetAsync(d_out, 0, (size_t)out_size * sizeof(float), stream);
    return;
  }
  _Float16* chs = (_Float16*)(ws + WS_CH);
  _Float16* cls = (_Float16*)(ws + WS_CL);
  _Float16* pvs = (_Float16*)(ws + WS_PV);
  float* cbsq = (float*)(ws + WS_CBSQ);
  float* topw = (float*)(ws + WS_TOP);
  float* ysc = (float*)(ws + WS_YSC);
  k0_zero<<<1, 1, 0, stream>>>(out);
  k2_pack<<<128, 256, 0, stream>>>(cb, chs, cls, pvs, cbsq);
  k3_main<<<1024, 256, 0, stream>>>(z_e, gum, chs, cls, cbsq, ysc, topw, out);
  k4_pv<<<1024, 256, 0, stream>>>(ysc, topw, pvs, out);
  k5_repair<<<256, 256, 0, stream>>>(z_e, cb, gum, topw, out);
}

// Round 2
// 793.558 us; speedup vs baseline: 1.0236x; 1.0236x over previous
//
#include <hip/hip_runtime.h>

#define BSZ 32
#define DIMD 256
#define WW 2048
#define SLOTS 1024
#define NROWS (BSZ*WW)
#define LOG_SLOTS 6.931471805599453f
#define THR 4.0f

#define ZQ_N (BSZ*DIMD*WW)
#define IDX_OFF ZQ_N
#define KL_OFF (ZQ_N + NROWS)
#define CM_OFF (KL_OFF + 1)

// workspace byte offsets
#define WS_CH   0u
#define WS_CL   524288u
#define WS_PV   1048576u
#define WS_CBSQ 1572864u
#define WS_TOP  1576960u
#define WS_NEED (1576960ull + 1048576ull)

typedef _Float16 half2_t __attribute__((ext_vector_type(2)));
typedef _Float16 half8_t __attribute__((ext_vector_type(8)));
typedef float v4f __attribute__((ext_vector_type(4)));

__device__ __forceinline__ void pmerge(float& m, float& s, float& t, float om, float os, float ot) {
  float M = fmaxf(m, om);
  float ea = __expf(m - M), eb = __expf(om - M);
  s = s * ea + os * eb;
  t = t * ea + ot * eb;
  m = M;
}

// merge two sorted top-3 lists (indices kept for top-2); ties -> smaller index wins
__device__ __forceinline__ void top3_merge(float& v1, float& i1, float& v2, float& i2, float& v3,
                                           float ov1, float oi1, float ov2, float oi2, float ov3) {
  bool sw = (ov1 > v1) || (ov1 == v1 && oi1 < i1);
  float a1v = sw ? ov1 : v1, a1i = sw ? oi1 : i1;
  float a2v = sw ? ov2 : v2, a2i = sw ? oi2 : i2;
  float a3v = sw ? ov3 : v3;
  float b1v = sw ? v1 : ov1, b1i = sw ? i1 : oi1;
  float b2v = sw ? v2 : ov2;
  bool a2w = (a2v > b1v) || (a2v == b1v && a2i < b1i);
  v1 = a1v; i1 = a1i;
  v2 = a2w ? a2v : b1v;
  i2 = a2w ? a2i : b1i;
  v3 = a2w ? fmaxf(a3v, b1v) : fmaxf(a2v, b2v);
}

__global__ void k0_zero(float* out) { out[KL_OFF] = 0.f; out[CM_OFF] = 0.f; }

// pack codebook: chs/cls = fp16 hi/lo B-fragment stream for QK^T;
// pvs = fp16 A-fragment stream for PV (A[d][slot] = cb[slot][d]); cbsq fp64->fp32
__global__ void k2_pack(const float* __restrict__ cb, _Float16* __restrict__ chs,
                        _Float16* __restrict__ cls, _Float16* __restrict__ pvs,
                        float* __restrict__ cbsq) {
  const int tid = blockIdx.x * 256 + threadIdx.x;
  if (tid < 32768) {
    const int lane = tid & 63;
    {
      const int ks = (tid >> 6) & 7, sblk = tid >> 9;
      const int col = sblk * 16 + (lane & 15);
      const int k0 = ks * 32 + (lane >> 4) * 8;
      half8_t vh, vl;
#pragma unroll
      for (int j = 0; j < 8; ++j) {
        const float v = cb[(size_t)col * DIMD + k0 + j];
        const _Float16 h = (_Float16)v;
        vh[j] = h;
        vl[j] = (_Float16)(v - (float)h);
      }
      *(half8_t*)&chs[(size_t)tid * 8] = vh;
      *(half8_t*)&cls[(size_t)tid * 8] = vl;
    }
    {
      // pvs: A-fragment for PV mfma: idx = cf*16+dt; lane row = d = dt*16+(lane&15),
      // k = slot-in-chunk = (lane>>4)*8 + j  (global slot = cf*32 + k)
      const int idx = tid >> 6;
      const int cf = idx >> 4, dt = idx & 15;
      const int d = dt * 16 + (lane & 15);
      const int s0 = cf * 32 + (lane >> 4) * 8;
      half8_t vp;
#pragma unroll
      for (int j = 0; j < 8; ++j)
        vp[j] = (_Float16)cb[(size_t)(s0 + j) * DIMD + d];
      *(half8_t*)&pvs[(size_t)tid * 8] = vp;
    }
  }
  if (tid < SLOTS) {
    double a = 0.0;
    for (int i = 0; i < DIMD; ++i) { const double v = (double)cb[(size_t)tid * DIMD + i]; a += v * v; }
    cbsq[tid] = (float)a;
  }
}

// fused: QK^T distances (fp16-split MFMA) + online probs stats + top3 + online-softmax PV
__launch_bounds__(256, 2)
__global__ void k3_main(const float* __restrict__ z_e, const float* __restrict__ gum,
                        const _Float16* __restrict__ chs, const _Float16* __restrict__ cls,
                        const float* __restrict__ cbsq, const _Float16* __restrict__ pvs,
                        float* __restrict__ topw, float* __restrict__ out) {
  __shared__ float cbsq_s[SLOTS];
  __shared__ _Float16 ubuf[4][16][40];   // per-wave u transpose buffer, 80B row stride
  __shared__ float rowbuf[4][16];        // per-wave row-max / row-sum broadcast

  const int t = threadIdx.x;
  for (int i = t; i < SLOTS; i += 256) cbsq_s[i] = cbsq[i];

  const int wv = t >> 6, lane = t & 63, l15 = lane & 15, lq = lane >> 4;
  const int r0 = blockIdx.x * 64;
  const int rw = r0 + wv * 16;               // wave's first global row
  const int b = r0 >> 11;
  const int w0 = r0 & 2047;

  // ---- load A fragments (z fp16 hi/lo) directly to registers ----
  // lane supplies A[row=l15][k=lq*8+j] for k-tile ks
  const float* zbase = z_e + (size_t)b * DIMD * WW + ((rw + l15) & 2047);
  half8_t ah[8], al[8];
  float zacc = 0.f;
#pragma unroll
  for (int ks = 0; ks < 8; ++ks) {
#pragma unroll
    for (int j = 0; j < 8; ++j) {
      const float v = zbase[(size_t)(ks * 32 + lq * 8 + j) * WW];
      zacc += v * v;
      const _Float16 h = (_Float16)v;
      ah[ks][j] = h;
      al[ks][j] = (_Float16)(v - (float)h);
    }
  }
  zacc += __shfl_xor(zacc, 16);
  zacc += __shfl_xor(zacc, 32);            // all lanes: ||z||^2 of row (rw + l15)
  float zs[4];
#pragma unroll
  for (int g = 0; g < 4; ++g) zs[g] = __shfl(zacc, lq * 4 + g);

  __syncthreads();                          // cbsq_s ready (only barrier)

  // state
  float m1[4], s1[4], t1[4], v1[4], v2[4], v3[4], i1[4], i2[4], s2[4], mr[4];
#pragma unroll
  for (int g = 0; g < 4; ++g) {
    m1[g] = -1e30f; s1[g] = 0.f; t1[g] = 0.f;
    v1[g] = -1e30f; v2[g] = -1e30f; v3[g] = -1e30f; i1[g] = 0.f; i2[g] = 0.f;
    s2[g] = 0.f; mr[g] = -1e30f;
  }
  float mcol = -1e30f;                      // running max for PV-column row (= row rw+l15)
  v4f pacc[16];
#pragma unroll
  for (int dt = 0; dt < 16; ++dt) pacc[dt] = v4f{0.f, 0.f, 0.f, 0.f};

  const float* gbase = gum + (size_t)rw * SLOTS;
  float gc[8];
#pragma unroll
  for (int c = 0; c < 2; ++c)
#pragma unroll
    for (int g = 0; g < 4; ++g)
      gc[c * 4 + g] = gbase[(size_t)(lq * 4 + g) * SLOTS + c * 16 + l15];

#pragma unroll 1
  for (int cf = 0; cf < 32; ++cf) {
    // prefetch gum for next chunk
    float gn[8];
    if (cf < 31) {
#pragma unroll
      for (int c = 0; c < 2; ++c)
#pragma unroll
        for (int g = 0; g < 4; ++g)
          gn[c * 4 + g] = gbase[(size_t)(lq * 4 + g) * SLOTS + (cf + 1) * 32 + c * 16 + l15];
    }
    // ---- QK^T: 2 slot-tiles x 8 k-steps x 3 (fp16 split) ----
    v4f qacc[2];
    qacc[0] = v4f{0.f, 0.f, 0.f, 0.f};
    qacc[1] = v4f{0.f, 0.f, 0.f, 0.f};
#pragma unroll
    for (int ks = 0; ks < 8; ++ks) {
#pragma unroll
      for (int c = 0; c < 2; ++c) {
        const size_t boff = ((size_t)((cf * 2 + c) * 8 + ks) * 64 + lane) * 8;
        const half8_t bh = *(const half8_t*)&chs[boff];
        const half8_t bl = *(const half8_t*)&cls[boff];
        qacc[c] = __builtin_amdgcn_mfma_f32_16x16x32_f16(ah[ks], bh, qacc[c], 0, 0, 0);
        qacc[c] = __builtin_amdgcn_mfma_f32_16x16x32_f16(al[ks], bh, qacc[c], 0, 0, 0);
        qacc[c] = __builtin_amdgcn_mfma_f32_16x16x32_f16(ah[ks], bl, qacc[c], 0, 0, 0);
      }
    }
    // ---- epilogue: distances, probs stats, top3, y ----
    float yv[8];
    float cmax[4] = {-1e30f, -1e30f, -1e30f, -1e30f};
#pragma unroll
    for (int c = 0; c < 2; ++c) {
      const int col = cf * 32 + c * 16 + l15;
      const float cq = cbsq_s[col];
      const float fc = (float)col;
#pragma unroll
      for (int g = 0; g < 4; ++g) {
        const float dd = cq + zs[g] - 2.f * qacc[c][g];
        const float lv = -dd;
        const float M = fmaxf(m1[g], lv);
        const float ea = __expf(m1[g] - M);
        const float eb = __expf(lv - M);
        s1[g] = s1[g] * ea + eb;
        t1[g] = t1[g] * ea + eb * dd;
        m1[g] = M;
        const float y = 2.f * (gc[c * 4 + g] - dd);
        yv[c * 4 + g] = y;
        const bool b1 = (y > v1[g]);
        const bool b2 = (y > v2[g]);
        const bool b3 = (y > v3[g]);
        v3[g] = b2 ? v2[g] : (b3 ? y : v3[g]);
        v2[g] = b1 ? v1[g] : (b2 ? y : v2[g]);
        i2[g] = b1 ? i1[g] : (b2 ? fc : i2[g]);
        v1[g] = b1 ? y : v1[g];
        i1[g] = b1 ? fc : i1[g];
        cmax[g] = fmaxf(cmax[g], y);
      }
    }
    // row-max across the 16-lane column group
#pragma unroll
    for (int mk = 1; mk < 16; mk <<= 1)
#pragma unroll
      for (int g = 0; g < 4; ++g) cmax[g] = fmaxf(cmax[g], __shfl_xor(cmax[g], mk));
    // broadcast row maxes to PV-column side (wave-local LDS, no barrier)
    if (l15 == 0) {
#pragma unroll
      for (int g = 0; g < 4; ++g) rowbuf[wv][lq * 4 + g] = cmax[g];
    }
    const float rmax = rowbuf[wv][l15];
    // column-side rescale (defer-max)
    const bool cresc = (rmax > mcol + THR);
    if (__any(cresc)) {
      const float f = cresc ? __expf(mcol - rmax) : 1.f;
#pragma unroll
      for (int dt = 0; dt < 16; ++dt) {
#pragma unroll
        for (int g = 0; g < 4; ++g) pacc[dt][g] *= f;
      }
      mcol = cresc ? rmax : mcol;
    }
    // writer-side rescale (same decision rule per row)
#pragma unroll
    for (int g = 0; g < 4; ++g) {
      if (cmax[g] > mr[g] + THR) {
        s2[g] *= __expf(mr[g] - cmax[g]);
        mr[g] = cmax[g];
      }
    }
    // u = exp(y - m_run), transpose-store to wave-local LDS
#pragma unroll
    for (int c = 0; c < 2; ++c)
#pragma unroll
      for (int g = 0; g < 4; ++g) {
        const float u = __expf(yv[c * 4 + g] - mr[g]);
        s2[g] += u;
        ubuf[wv][lq * 4 + g][c * 16 + l15] = (_Float16)u;
      }
    // ---- PV: C[d][w] += V^T-frag @ u-frag ----
    const half8_t pa = *(const half8_t*)&ubuf[wv][l15][lq * 8];
#pragma unroll
    for (int dt = 0; dt < 16; ++dt) {
      const half8_t pb = *(const half8_t*)&pvs[((size_t)(cf * 16 + dt) * 64 + lane) * 8];
      pacc[dt] = __builtin_amdgcn_mfma_f32_16x16x32_f16(pb, pa, pacc[dt], 0, 0, 0);
    }
    if (cf < 31) {
#pragma unroll
      for (int i = 0; i < 8; ++i) gc[i] = gn[i];
    }
  }

  // ---- finalize: merge stats across the 16-lane group ----
#pragma unroll
  for (int mk = 1; mk < 16; mk <<= 1) {
#pragma unroll
    for (int g = 0; g < 4; ++g) {
      const float om = __shfl_xor(m1[g], mk);
      const float os = __shfl_xor(s1[g], mk);
      const float ot = __shfl_xor(t1[g], mk);
      pmerge(m1[g], s1[g], t1[g], om, os, ot);
      const float ov1 = __shfl_xor(v1[g], mk);
      const float oi1 = __shfl_xor(i1[g], mk);
      const float ov2 = __shfl_xor(v2[g], mk);
      const float oi2 = __shfl_xor(i2[g], mk);
      const float ov3 = __shfl_xor(v3[g], mk);
      top3_merge(v1[g], i1[g], v2[g], i2[g], v3[g], ov1, oi1, ov2, oi2, ov3);
      // s2 needs matching scale before adding: mr is group-uniform, so plain add
      s2[g] += __shfl_xor(s2[g], mk);
    }
  }
  float klsum = 0.f, cmsum = 0.f;
#pragma unroll
  for (int g = 0; g < 4; ++g) {
    const float commit_row = t1[g] / s1[g];
    const float lse = m1[g] + logf(s1[g]);
    klsum += -commit_row - lse + LOG_SLOTS;
    cmsum += commit_row;
    if (l15 == 0) {
      const int row = rw + lq * 4 + g;
      out[IDX_OFF + row] = i1[g];
      float4 tv; tv.x = v1[g]; tv.y = v2[g]; tv.z = v3[g]; tv.w = i2[g];
      *(float4*)&topw[(size_t)row * 4] = tv;
    }
  }
  // broadcast row u-sums to PV-column side
  if (l15 == 0) {
#pragma unroll
    for (int g = 0; g < 4; ++g) rowbuf[wv][lq * 4 + g] = s2[g];
  }
  const float inv = 1.f / rowbuf[wv][l15];
  // z_q^T store: d = dt*16 + lq*4 + g, w = w0 + wv*16 + l15 (coalesced in w)
#pragma unroll
  for (int dt = 0; dt < 16; ++dt)
#pragma unroll
    for (int g = 0; g < 4; ++g)
      out[((size_t)b * DIMD + dt * 16 + lq * 4 + g) * WW + w0 + wv * 16 + l15] = pacc[dt][g] * inv;

  // kl/commit: one contribution per row (l15==0 lanes), wave-reduce, one atomic per value
  float kw = (l15 == 0) ? klsum : 0.f;
  float cw = (l15 == 0) ? cmsum : 0.f;
#pragma unroll
  for (int mk = 1; mk < 64; mk <<= 1) { kw += __shfl_xor(kw, mk); cw += __shfl_xor(cw, mk); }
  if (lane == 0) {
    atomicAdd(&out[KL_OFF], kw * 0.03125f);
    atomicAdd(&out[CM_OFF], cw * 0.03125f);
  }
}

// fp64 argmax repair for near-tie rows
__global__ void k5_repair(const float* __restrict__ z_e, const float* __restrict__ cb,
                          const float* __restrict__ gum, const float* __restrict__ topw,
                          float* __restrict__ out) {
  const int wv = threadIdx.x >> 6, lane = threadIdx.x & 63;
#pragma unroll 1
  for (int rr = 0; rr < 64; ++rr) {
    const int r = blockIdx.x * 256 + wv * 64 + rr;
    const float4 tw = *(const float4*)&topw[(size_t)r * 4];
    if (tw.x - tw.y >= 0.02f) continue;
    const int b = r >> 11, w = r & 2047;
    double zd[4]; double zq = 0.0;
#pragma unroll
    for (int i = 0; i < 4; ++i) {
      const float zz = z_e[((size_t)b * DIMD + lane + i * 64) * WW + w];
      zd[i] = (double)zz; zq += zd[i] * zd[i];
    }
#pragma unroll
    for (int mk = 1; mk < 64; mk <<= 1) zq += __shfl_xor(zq, mk);
    const int c1 = (int)out[IDX_OFF + r];
    const int c2 = (int)tw.w;
    const bool full = (tw.x - tw.z < 0.02f);
    double bestv = -1e300; int besti = 0;
    const int nc = full ? SLOTS : 2;
    for (int ci = 0; ci < nc; ++ci) {
      const int s = full ? ci : (ci == 0 ? c1 : c2);
      double dot = 0.0, csq = 0.0;
#pragma unroll
      for (int i = 0; i < 4; ++i) {
        const double cv = (double)cb[(size_t)s * DIMD + lane + i * 64];
        dot += zd[i] * cv; csq += cv * cv;
      }
#pragma unroll
      for (int mk = 1; mk < 64; mk <<= 1) { dot += __shfl_xor(dot, mk); csq += __shfl_xor(csq, mk); }
      const double y = 2.0 * ((double)gum[(size_t)r * SLOTS + s] - (csq + zq - 2.0 * dot));
      if (y > bestv || (y == bestv && s < besti)) { bestv = y; besti = s; }
    }
    if (lane == 0) out[IDX_OFF + r] = (float)besti;
  }
}

extern "C" void kernel_launch(void* const* d_in, const int* in_sizes, int n_in,
                              void* d_out, int out_size, void* d_ws, size_t ws_size,
                              hipStream_t stream) {
  const float* z_e = (const float*)d_in[0];
  const float* cb  = (const float*)d_in[1];
  const float* gum = (const float*)d_in[2];
  float* out = (float*)d_out;
  char* ws = (char*)d_ws;
  if (ws_size < WS_NEED) {
    hipMemsetAsync(d_out, 0, (size_t)out_size * sizeof(float), stream);
    return;
  }
  _Float16* chs = (_Float16*)(ws + WS_CH);
  _Float16* cls = (_Float16*)(ws + WS_CL);
  _Float16* pvs = (_Float16*)(ws + WS_PV);
  float* cbsq = (float*)(ws + WS_CBSQ);
  float* topw = (float*)(ws + WS_TOP);
  k0_zero<<<1, 1, 0, stream>>>(out);
  k2_pack<<<128, 256, 0, stream>>>(cb, chs, cls, pvs, cbsq);
  k3_main<<<1024, 256, 0, stream>>>(z_e, gum, chs, cls, cbsq, pvs, topw, out);
  k5_repair<<<256, 256, 0, stream>>>(z_e, cb, gum, topw, out);
}